// Round 7
// baseline (872.417 us; speedup 1.0000x reference)
//
#include <hip/hip_runtime.h>
#include <hip/hip_bf16.h>

#define N_NODES 100000
#define N_EDGES 1600000
#define IN_DIM 128
#define HID 64
#define NB 391                 // buckets of 256 dst nodes
#define EPB 4096               // edges per k_bucket block
#define BUCKET_BLOCKS ((N_EDGES + EPB - 1) / EPB)  // 391
#define MAXPB 8192             // fixed gbuf region per bucket (mean 4092)
#define ASTRIDE 65             // acc row stride (odd -> spread LDS banks)

typedef __attribute__((ext_vector_type(8))) short bf16x8;
typedef __attribute__((ext_vector_type(4))) float f32x4;

// ---------------- threefry2x32, key = (0, 42) ----------------
__device__ __forceinline__ unsigned rotl32(unsigned x, unsigned r) {
    return (x << r) | (x >> (32u - r));
}

__device__ __forceinline__ void threefry2x32_k42(unsigned x0, unsigned x1,
                                                 unsigned& o0, unsigned& o1) {
    const unsigned ks0 = 0u;
    const unsigned ks1 = 42u;
    const unsigned ks2 = 0u ^ 42u ^ 0x1BD11BDAu;
    x0 += ks0; x1 += ks1;
    x0 += x1; x1 = rotl32(x1, 13); x1 ^= x0;
    x0 += x1; x1 = rotl32(x1, 15); x1 ^= x0;
    x0 += x1; x1 = rotl32(x1, 26); x1 ^= x0;
    x0 += x1; x1 = rotl32(x1, 6);  x1 ^= x0;
    x0 += ks1; x1 += ks2 + 1u;
    x0 += x1; x1 = rotl32(x1, 17); x1 ^= x0;
    x0 += x1; x1 = rotl32(x1, 29); x1 ^= x0;
    x0 += x1; x1 = rotl32(x1, 16); x1 ^= x0;
    x0 += x1; x1 = rotl32(x1, 24); x1 ^= x0;
    x0 += ks2; x1 += ks0 + 2u;
    x0 += x1; x1 = rotl32(x1, 13); x1 ^= x0;
    x0 += x1; x1 = rotl32(x1, 15); x1 ^= x0;
    x0 += x1; x1 = rotl32(x1, 26); x1 ^= x0;
    x0 += x1; x1 = rotl32(x1, 6);  x1 ^= x0;
    x0 += ks0; x1 += ks1 + 3u;
    x0 += x1; x1 = rotl32(x1, 17); x1 ^= x0;
    x0 += x1; x1 = rotl32(x1, 29); x1 ^= x0;
    x0 += x1; x1 = rotl32(x1, 16); x1 ^= x0;
    x0 += x1; x1 = rotl32(x1, 24); x1 ^= x0;
    x0 += ks1; x1 += ks2 + 4u;
    x0 += x1; x1 = rotl32(x1, 13); x1 ^= x0;
    x0 += x1; x1 = rotl32(x1, 15); x1 ^= x0;
    x0 += x1; x1 = rotl32(x1, 26); x1 ^= x0;
    x0 += x1; x1 = rotl32(x1, 6);  x1 ^= x0;
    x0 += ks2; x1 += ks0 + 5u;
    o0 = x0; o1 = x1;
}

__device__ __forceinline__ float bf2f(unsigned short u) {
    return __uint_as_float((unsigned)u << 16);
}
__device__ __forceinline__ float bf2f_lo(unsigned u) {
    return __uint_as_float(u << 16);
}
__device__ __forceinline__ float bf2f_hi(unsigned u) {
    return __uint_as_float(u & 0xffff0000u);
}
__device__ __forceinline__ uint2 loadg(const unsigned short* __restrict__ gm, int ri, int d4) {
    return *(const uint2*)(gm + ((size_t)ri << 6) + (d4 << 2));
}

// ---- phase 1: bucketed scatter into FIXED regions (r5-proven) + degree count ----
// record = (c & 255) << 17 | r   (r < 2^17). LDS count+scan+permute makes the
// global write segmented-contiguous per bucket. deg[] via global atomics
// (fire-and-forget, 400 KB L2-resident) replaces the CSR kernel's counting.
__global__ __launch_bounds__(512) void k_bucket(const int* __restrict__ src,
                                                const int* __restrict__ dst,
                                                int* __restrict__ bucketcnt,
                                                int* __restrict__ deg,
                                                unsigned* __restrict__ gbuf) {
    __shared__ int cnt[512];
    __shared__ int off[512];
    __shared__ int cur[NB];
    __shared__ int gbase[NB];
    __shared__ unsigned buf[EPB];
    __shared__ unsigned short bkt[EPB];
    const int t = threadIdx.x;
    const int e0 = blockIdx.x * EPB;
    const int n = min(EPB, N_EDGES - e0);
    cnt[t] = 0;
    __syncthreads();
    unsigned myrec[EPB / 512];
    int myb[EPB / 512];
#pragma unroll
    for (int k = 0; k < EPB / 512; k++) {
        int e = e0 + k * 512 + t;
        if (e < N_EDGES) {
            int r = src[e];
            int c = dst[e];
            int b = c >> 8;
            myrec[k] = ((unsigned)(c & 255) << 17) | (unsigned)r;
            myb[k] = b;
            atomicAdd(&cnt[b], 1);
            atomicAdd(&deg[c], 1);          // in-degree (self-loop added later)
        } else {
            myb[k] = -1;
        }
    }
    __syncthreads();
    int own = cnt[t];
    for (int o = 1; o < 512; o <<= 1) {
        int v = (t >= o) ? cnt[t - o] : 0;
        __syncthreads();
        cnt[t] += v;
        __syncthreads();
    }
    off[t] = cnt[t] - own;  // exclusive prefix (records sorted by bucket in buf)
    if (t < NB) {
        cur[t] = off[t];
        gbase[t] = t * MAXPB + (own ? atomicAdd(&bucketcnt[t], own) : 0);
    }
    __syncthreads();
#pragma unroll
    for (int k = 0; k < EPB / 512; k++) {
        if (myb[k] >= 0) {
            int p = atomicAdd(&cur[myb[k]], 1);
            buf[p] = myrec[k];
            bkt[p] = (unsigned short)myb[k];
        }
    }
    __syncthreads();
    for (int j = t; j < n; j += 512) {
        int b = bkt[j];
        gbuf[gbase[b] + (j - off[b])] = buf[j];
    }
}

// ------ g = (x @ W_conv) * dinv[row], bf16 out — MFMA split-bf16 version ------
// 3-pass split: x=xh+xl, W=Wh+Wl (bf16 each); h = xh@Wh + xl@Wh + xh@Wl.
// dinv computed inline from deg (rsqrtf(deg+1)) — no dinv array needed.
__global__ __launch_bounds__(256) void k_gemm(const float* __restrict__ x,
                                              const float* __restrict__ W,
                                              const int* __restrict__ deg,
                                              unsigned short* __restrict__ gm) {
    __shared__ unsigned short WtH[HID][136];
    __shared__ unsigned short WtL[HID][136];
    const int t = threadIdx.x;
    {
        const int n = t & 63;
        const int k0 = (t >> 6) * 32;
        for (int k = k0; k < k0 + 32; k += 2) {
            float w0 = W[(size_t)k * HID + n];
            float w1 = W[(size_t)(k + 1) * HID + n];
            unsigned short h0 = __bfloat16_as_ushort(__float2bfloat16(w0));
            unsigned short h1 = __bfloat16_as_ushort(__float2bfloat16(w1));
            unsigned short l0 = __bfloat16_as_ushort(__float2bfloat16(w0 - bf2f(h0)));
            unsigned short l1 = __bfloat16_as_ushort(__float2bfloat16(w1 - bf2f(h1)));
            *(unsigned*)&WtH[n][k] = (unsigned)h0 | ((unsigned)h1 << 16);
            *(unsigned*)&WtL[n][k] = (unsigned)l0 | ((unsigned)l1 << 16);
        }
    }
    __syncthreads();

    const int wave = t >> 6, lane = t & 63;
    const int row16 = lane & 15;   // A-frag row within tile / B-frag col
    const int kgrp = lane >> 4;    // k-subgroup
    const int browA = blockIdx.x * 64 + wave * 16;

    const int rA = min(browA + row16, N_NODES - 1);  // clamp tail reads
    const float* xr = x + (size_t)rA * IN_DIM + kgrp * 8;
    float xv[32];
#pragma unroll
    for (int ks = 0; ks < 4; ks++) {
        *(f32x4*)&xv[ks * 8]     = *(const f32x4*)(xr + ks * 32);
        *(f32x4*)&xv[ks * 8 + 4] = *(const f32x4*)(xr + ks * 32 + 4);
    }
    bf16x8 ah[4], al[4];
#pragma unroll
    for (int ks = 0; ks < 4; ks++) {
#pragma unroll
        for (int j = 0; j < 8; j++) {
            float v = xv[ks * 8 + j];
            unsigned short h = __bfloat16_as_ushort(__float2bfloat16(v));
            unsigned short l = __bfloat16_as_ushort(__float2bfloat16(v - bf2f(h)));
            ah[ks][j] = (short)h;
            al[ks][j] = (short)l;
        }
    }

    float dv[4];
    int orow[4];
#pragma unroll
    for (int i = 0; i < 4; i++) {
        orow[i] = browA + kgrp * 4 + i;
        dv[i] = rsqrtf((float)(deg[min(orow[i], N_NODES - 1)] + 1));
    }

#pragma unroll
    for (int nt = 0; nt < 4; nt++) {
        const int n = nt * 16 + row16;
        bf16x8 bh[4], bl[4];
#pragma unroll
        for (int ks = 0; ks < 4; ks++) {
            bh[ks] = *(const bf16x8*)&WtH[n][ks * 32 + kgrp * 8];
            bl[ks] = *(const bf16x8*)&WtL[n][ks * 32 + kgrp * 8];
        }
        f32x4 acc = {0.f, 0.f, 0.f, 0.f};
#pragma unroll
        for (int ks = 0; ks < 4; ks++)
            acc = __builtin_amdgcn_mfma_f32_16x16x32_bf16(ah[ks], bh[ks], acc, 0, 0, 0);
#pragma unroll
        for (int ks = 0; ks < 4; ks++)
            acc = __builtin_amdgcn_mfma_f32_16x16x32_bf16(al[ks], bh[ks], acc, 0, 0, 0);
#pragma unroll
        for (int ks = 0; ks < 4; ks++)
            acc = __builtin_amdgcn_mfma_f32_16x16x32_bf16(ah[ks], bl[ks], acc, 0, 0, 0);
#pragma unroll
        for (int i = 0; i < 4; i++) {
            if (orow[i] < N_NODES) {
                float g = acc[i] * dv[i];
                gm[(size_t)orow[i] * HID + nt * 16 + row16] =
                    __bfloat16_as_ushort(__float2bfloat16(g));
            }
        }
    }
}

// ------- k_aggr2: bucket-direct aggregation (CSR kernel ELIMINATED) -------
// One block per bucket (391 x 512 thr). Streams the bucket's RAW records,
// gathers g rows (16 lanes x uint2, 2-deep ping-pong like r5's proven loop),
// accumulates into per-bucket LDS fp32 acc[256][ASTRIDE] via ds_add_f32.
// Epilogue: + self g[c], * rsqrtf(deg+1), bias/relu/dropout, [64->2] matvec.
__global__ __launch_bounds__(512) void k_aggr2(const unsigned short* __restrict__ gm,
                                               const unsigned* __restrict__ gbuf,
                                               const int* __restrict__ bucketcnt,
                                               const int* __restrict__ deg,
                                               const float* __restrict__ bconv,
                                               const float* __restrict__ Wlin,
                                               const float* __restrict__ blin,
                                               float* __restrict__ out) {
    __shared__ float acc[256 * ASTRIDE];  // 66.5 KB
    const int b = blockIdx.x, t = threadIdx.x;
    const int n = bucketcnt[b];
    for (int i = t; i < 256 * ASTRIDE; i += 512) acc[i] = 0.f;
    __syncthreads();
    const int g = t >> 4, d4 = t & 15;  // 32 groups x 16 lanes
    const unsigned* rec = gbuf + (size_t)b * MAXPB;

    if (n > 0) {
        const int last = n - 1;
        unsigned ra[8], rb2[8];
        uint2 wa[8], wb[8];
        int s = g * 8;  // group g covers records {g*8+u + 256*k}
#pragma unroll
        for (int u = 0; u < 8; u++) ra[u] = rec[min(s + u, last)];
#pragma unroll
        for (int u = 0; u < 8; u++) wa[u] = loadg(gm, (int)(ra[u] & 0x1FFFFu), d4);
        bool haveB = (s + 256 < n);
        if (haveB) {
#pragma unroll
            for (int u = 0; u < 8; u++) rb2[u] = rec[min(s + 256 + u, last)];
#pragma unroll
            for (int u = 0; u < 8; u++) wb[u] = loadg(gm, (int)(rb2[u] & 0x1FFFFu), d4);
        }
        while (true) {
            // accumulate batch A for [s, s+8) — masked adds are exact +0.0f
#pragma unroll
            for (int u = 0; u < 8; u++) {
                const unsigned m = (s + u < n) ? 0xffffffffu : 0u;
                float* ap = &acc[(int)(ra[u] >> 17) * ASTRIDE + (d4 << 2)];
                atomicAdd(ap + 0, bf2f_lo(wa[u].x & m));
                atomicAdd(ap + 1, bf2f_hi(wa[u].x & m));
                atomicAdd(ap + 2, bf2f_lo(wa[u].y & m));
                atomicAdd(ap + 3, bf2f_hi(wa[u].y & m));
            }
            s += 256;
            if (!haveB) break;
            const bool haveN = (s + 256 < n);
            if (haveN) {
#pragma unroll
                for (int u = 0; u < 8; u++) ra[u] = rec[min(s + 256 + u, last)];
#pragma unroll
                for (int u = 0; u < 8; u++) wa[u] = loadg(gm, (int)(ra[u] & 0x1FFFFu), d4);
            }
            // accumulate batch B for [s, s+8)
#pragma unroll
            for (int u = 0; u < 8; u++) {
                const unsigned m = (s + u < n) ? 0xffffffffu : 0u;
                float* ap = &acc[(int)(rb2[u] >> 17) * ASTRIDE + (d4 << 2)];
                atomicAdd(ap + 0, bf2f_lo(wb[u].x & m));
                atomicAdd(ap + 1, bf2f_hi(wb[u].x & m));
                atomicAdd(ap + 2, bf2f_lo(wb[u].y & m));
                atomicAdd(ap + 3, bf2f_hi(wb[u].y & m));
            }
            s += 256;
            if (!haveN) break;
            haveB = (s + 256 < n);
            if (haveB) {
#pragma unroll
                for (int u = 0; u < 8; u++) rb2[u] = rec[min(s + 256 + u, last)];
#pragma unroll
                for (int u = 0; u < 8; u++) wb[u] = loadg(gm, (int)(rb2[u] & 0x1FFFFu), d4);
            }
        }
    }
    __syncthreads();

    // epilogue: 8 passes x 32 dsts; group handles (c, all 16 dim-quads)
#pragma unroll
    for (int p = 0; p < 8; p++) {
        const int cl = p * 32 + g;
        const int c = b * 256 + cl;
        if (c >= N_NODES) continue;  // whole 16-lane group agrees
        const float* ap = &acc[cl * ASTRIDE + (d4 << 2)];
        float a0 = ap[0], a1 = ap[1], a2 = ap[2], a3 = ap[3];
        const uint2 s0 = loadg(gm, c, d4);  // self-loop term
        a0 += bf2f_lo(s0.x); a1 += bf2f_hi(s0.x);
        a2 += bf2f_lo(s0.y); a3 += bf2f_hi(s0.y);

        const float dv = rsqrtf((float)(deg[c] + 1));
        const float4 bc4 = *(const float4*)(bconv + (d4 << 2));
        float v0 = fmaxf(a0 * dv + bc4.x, 0.f);
        float v1 = fmaxf(a1 * dv + bc4.y, 0.f);
        float v2 = fmaxf(a2 * dv + bc4.z, 0.f);
        float v3 = fmaxf(a3 * dv + bc4.w, 0.f);

        // dropout: per-element threefry mapping i = c*64 + d
        const unsigned ib = (unsigned)(c * HID + (d4 << 2));
        unsigned o0, o1;
        threefry2x32_k42(0u, ib + 0u, o0, o1);
        v0 = ((o0 ^ o1) & 0x80000000u) ? 0.f : v0 * 2.f;
        threefry2x32_k42(0u, ib + 1u, o0, o1);
        v1 = ((o0 ^ o1) & 0x80000000u) ? 0.f : v1 * 2.f;
        threefry2x32_k42(0u, ib + 2u, o0, o1);
        v2 = ((o0 ^ o1) & 0x80000000u) ? 0.f : v2 * 2.f;
        threefry2x32_k42(0u, ib + 3u, o0, o1);
        v3 = ((o0 ^ o1) & 0x80000000u) ? 0.f : v3 * 2.f;

        // [64 -> 2] matvec partials: Wlin row-major [64][2]
        const float4 wl0 = *(const float4*)(Wlin + (d4 << 3));
        const float4 wl1 = *(const float4*)(Wlin + (d4 << 3) + 4);
        float p0 = v0 * wl0.x + v1 * wl0.z + v2 * wl1.x + v3 * wl1.z;
        float p1 = v0 * wl0.y + v1 * wl0.w + v2 * wl1.y + v3 * wl1.w;

        // reduce across the 16 lanes of this group (xor masks stay in-group)
#pragma unroll
        for (int off = 8; off; off >>= 1) {
            p0 += __shfl_xor(p0, off);
            p1 += __shfl_xor(p1, off);
        }
        if (d4 == 0) {
            *(float2*)(out + (size_t)c * 2) = make_float2(p0 + blin[0], p1 + blin[1]);
        }
    }
}

extern "C" void kernel_launch(void* const* d_in, const int* in_sizes, int n_in,
                              void* d_out, int out_size, void* d_ws, size_t ws_size,
                              hipStream_t stream) {
    // Map inputs BY ELEMENT COUNT (all unique) — robust to positional order.
    const float* x  = (const float*)d_in[0];
    const void*  ei = d_in[1];
    const float* Wc = (const float*)d_in[2];
    const float* bc = (const float*)d_in[3];
    const float* Wl = (const float*)d_in[4];
    const float* bl = (const float*)d_in[5];
    for (int i = 0; i < n_in; i++) {
        switch (in_sizes[i]) {
            case N_NODES * IN_DIM:   x  = (const float*)d_in[i]; break;
            case 2 * N_EDGES:
            case 4 * N_EDGES:        ei = d_in[i]; break;
            case IN_DIM * HID:       Wc = (const float*)d_in[i]; break;
            case HID:                bc = (const float*)d_in[i]; break;
            case HID * 2:            Wl = (const float*)d_in[i]; break;
            case 2:                  bl = (const float*)d_in[i]; break;
            default: break;
        }
    }
    float* out = (float*)d_out;

    const int* src = (const int*)ei;            // edge_index[0] (int32, proven r2≡r3)
    const int* dst = (const int*)ei + N_EDGES;  // edge_index[1]

    char* ws = (char*)d_ws;
    size_t off = 0;
    unsigned short* gm = (unsigned short*)(ws + off); off += (size_t)N_NODES * HID * 2;  // 12.8 MB
    int* deg           = (int*)(ws + off);     off += (size_t)N_NODES * 4;               // 400 KB
    int* bucketcnt     = (int*)(ws + off);     off += (size_t)(NB + 64) * 4;             // adjacent to deg
    off = (off + 255) & ~(size_t)255;
    unsigned* gbuf     = (unsigned*)(ws + off); off += (size_t)NB * MAXPB * 4;           // 12.8 MB
    // gbuf holds raw records; consumed directly by k_aggr2 (no CSR pass)

    // zero deg + bucketcnt in one memset (contiguous)
    hipMemsetAsync(deg, 0, ((size_t)N_NODES + NB) * 4, stream);
    k_bucket<<<BUCKET_BLOCKS, 512, 0, stream>>>(src, dst, bucketcnt, deg, gbuf);
    k_gemm<<<(N_NODES + 63) / 64, 256, 0, stream>>>(x, Wc, deg, gm);
    k_aggr2<<<NB, 512, 0, stream>>>(gm, gbuf, bucketcnt, deg, bc, Wl, bl, out);
}

// Round 8
// 234.898 us; speedup vs baseline: 3.7140x; 3.7140x over previous
//
#include <hip/hip_runtime.h>
#include <hip/hip_bf16.h>

#define N_NODES 100000
#define N_EDGES 1600000
#define IN_DIM 128
#define HID 64
#define NB 391                 // buckets of 256 dst nodes
#define EPB 4096               // edges per k_bucket block
#define BUCKET_BLOCKS ((N_EDGES + EPB - 1) / EPB)  // 391
#define MAXPB 8192             // fixed gbuf region per bucket (mean 4092)

typedef __attribute__((ext_vector_type(8))) short bf16x8;
typedef __attribute__((ext_vector_type(4))) float f32x4;

// ---------------- threefry2x32, key = (0, 42) ----------------
__device__ __forceinline__ unsigned rotl32(unsigned x, unsigned r) {
    return (x << r) | (x >> (32u - r));
}

__device__ __forceinline__ void threefry2x32_k42(unsigned x0, unsigned x1,
                                                 unsigned& o0, unsigned& o1) {
    const unsigned ks0 = 0u;
    const unsigned ks1 = 42u;
    const unsigned ks2 = 0u ^ 42u ^ 0x1BD11BDAu;
    x0 += ks0; x1 += ks1;
    x0 += x1; x1 = rotl32(x1, 13); x1 ^= x0;
    x0 += x1; x1 = rotl32(x1, 15); x1 ^= x0;
    x0 += x1; x1 = rotl32(x1, 26); x1 ^= x0;
    x0 += x1; x1 = rotl32(x1, 6);  x1 ^= x0;
    x0 += ks1; x1 += ks2 + 1u;
    x0 += x1; x1 = rotl32(x1, 17); x1 ^= x0;
    x0 += x1; x1 = rotl32(x1, 29); x1 ^= x0;
    x0 += x1; x1 = rotl32(x1, 16); x1 ^= x0;
    x0 += x1; x1 = rotl32(x1, 24); x1 ^= x0;
    x0 += ks2; x1 += ks0 + 2u;
    x0 += x1; x1 = rotl32(x1, 13); x1 ^= x0;
    x0 += x1; x1 = rotl32(x1, 15); x1 ^= x0;
    x0 += x1; x1 = rotl32(x1, 26); x1 ^= x0;
    x0 += x1; x1 = rotl32(x1, 6);  x1 ^= x0;
    x0 += ks0; x1 += ks1 + 3u;
    x0 += x1; x1 = rotl32(x1, 17); x1 ^= x0;
    x0 += x1; x1 = rotl32(x1, 29); x1 ^= x0;
    x0 += x1; x1 = rotl32(x1, 16); x1 ^= x0;
    x0 += x1; x1 = rotl32(x1, 24); x1 ^= x0;
    x0 += ks1; x1 += ks2 + 4u;
    x0 += x1; x1 = rotl32(x1, 13); x1 ^= x0;
    x0 += x1; x1 = rotl32(x1, 15); x1 ^= x0;
    x0 += x1; x1 = rotl32(x1, 26); x1 ^= x0;
    x0 += x1; x1 = rotl32(x1, 6);  x1 ^= x0;
    x0 += ks2; x1 += ks0 + 5u;
    o0 = x0; o1 = x1;
}

__device__ __forceinline__ float bf2f(unsigned short u) {
    return __uint_as_float((unsigned)u << 16);
}
__device__ __forceinline__ float bf2f_lo(unsigned u) {
    return __uint_as_float(u << 16);
}
__device__ __forceinline__ float bf2f_hi(unsigned u) {
    return __uint_as_float(u & 0xffff0000u);
}
__device__ __forceinline__ uint2 loadg(const unsigned short* __restrict__ gm, int ri, int d4) {
    return *(const uint2*)(gm + ((size_t)ri << 6) + (d4 << 2));
}

// ---- phase 1: bucketed scatter into FIXED regions (r5-proven) + degree count ----
// record = (c & 255) << 17 | r   (r < 2^17). LDS count+scan+permute makes the
// global write segmented-contiguous per bucket. deg[] via global int atomics
// (fire-and-forget, 400 KB L2-resident) — proven in r7.
__global__ __launch_bounds__(512) void k_bucket(const int* __restrict__ src,
                                                const int* __restrict__ dst,
                                                int* __restrict__ bucketcnt,
                                                int* __restrict__ deg,
                                                unsigned* __restrict__ gbuf) {
    __shared__ int cnt[512];
    __shared__ int off[512];
    __shared__ int cur[NB];
    __shared__ int gbase[NB];
    __shared__ unsigned buf[EPB];
    __shared__ unsigned short bkt[EPB];
    const int t = threadIdx.x;
    const int e0 = blockIdx.x * EPB;
    const int n = min(EPB, N_EDGES - e0);
    cnt[t] = 0;
    __syncthreads();
    unsigned myrec[EPB / 512];
    int myb[EPB / 512];
#pragma unroll
    for (int k = 0; k < EPB / 512; k++) {
        int e = e0 + k * 512 + t;
        if (e < N_EDGES) {
            int r = src[e];
            int c = dst[e];
            int b = c >> 8;
            myrec[k] = ((unsigned)(c & 255) << 17) | (unsigned)r;
            myb[k] = b;
            atomicAdd(&cnt[b], 1);
            atomicAdd(&deg[c], 1);          // in-degree (self-loop added later)
        } else {
            myb[k] = -1;
        }
    }
    __syncthreads();
    int own = cnt[t];
    for (int o = 1; o < 512; o <<= 1) {
        int v = (t >= o) ? cnt[t - o] : 0;
        __syncthreads();
        cnt[t] += v;
        __syncthreads();
    }
    off[t] = cnt[t] - own;  // exclusive prefix (records sorted by bucket in buf)
    if (t < NB) {
        cur[t] = off[t];
        gbase[t] = t * MAXPB + (own ? atomicAdd(&bucketcnt[t], own) : 0);
    }
    __syncthreads();
#pragma unroll
    for (int k = 0; k < EPB / 512; k++) {
        if (myb[k] >= 0) {
            int p = atomicAdd(&cur[myb[k]], 1);
            buf[p] = myrec[k];
            bkt[p] = (unsigned short)myb[k];
        }
    }
    __syncthreads();
    for (int j = t; j < n; j += 512) {
        int b = bkt[j];
        gbuf[gbase[b] + (j - off[b])] = buf[j];
    }
}

// ------ g = (x @ W_conv) * dinv[row], bf16 out — MFMA split-bf16 (r7-proven) ------
// 3-pass split: x=xh+xl, W=Wh+Wl (bf16 each); h = xh@Wh + xl@Wh + xh@Wl.
// dinv computed inline from deg (rsqrtf(deg+1)).
__global__ __launch_bounds__(256) void k_gemm(const float* __restrict__ x,
                                              const float* __restrict__ W,
                                              const int* __restrict__ deg,
                                              unsigned short* __restrict__ gm) {
    __shared__ unsigned short WtH[HID][136];
    __shared__ unsigned short WtL[HID][136];
    const int t = threadIdx.x;
    {
        const int n = t & 63;
        const int k0 = (t >> 6) * 32;
        for (int k = k0; k < k0 + 32; k += 2) {
            float w0 = W[(size_t)k * HID + n];
            float w1 = W[(size_t)(k + 1) * HID + n];
            unsigned short h0 = __bfloat16_as_ushort(__float2bfloat16(w0));
            unsigned short h1 = __bfloat16_as_ushort(__float2bfloat16(w1));
            unsigned short l0 = __bfloat16_as_ushort(__float2bfloat16(w0 - bf2f(h0)));
            unsigned short l1 = __bfloat16_as_ushort(__float2bfloat16(w1 - bf2f(h1)));
            *(unsigned*)&WtH[n][k] = (unsigned)h0 | ((unsigned)h1 << 16);
            *(unsigned*)&WtL[n][k] = (unsigned)l0 | ((unsigned)l1 << 16);
        }
    }
    __syncthreads();

    const int wave = t >> 6, lane = t & 63;
    const int row16 = lane & 15;   // A-frag row within tile / B-frag col
    const int kgrp = lane >> 4;    // k-subgroup
    const int browA = blockIdx.x * 64 + wave * 16;

    const int rA = min(browA + row16, N_NODES - 1);  // clamp tail reads
    const float* xr = x + (size_t)rA * IN_DIM + kgrp * 8;
    float xv[32];
#pragma unroll
    for (int ks = 0; ks < 4; ks++) {
        *(f32x4*)&xv[ks * 8]     = *(const f32x4*)(xr + ks * 32);
        *(f32x4*)&xv[ks * 8 + 4] = *(const f32x4*)(xr + ks * 32 + 4);
    }
    bf16x8 ah[4], al[4];
#pragma unroll
    for (int ks = 0; ks < 4; ks++) {
#pragma unroll
        for (int j = 0; j < 8; j++) {
            float v = xv[ks * 8 + j];
            unsigned short h = __bfloat16_as_ushort(__float2bfloat16(v));
            unsigned short l = __bfloat16_as_ushort(__float2bfloat16(v - bf2f(h)));
            ah[ks][j] = (short)h;
            al[ks][j] = (short)l;
        }
    }

    float dv[4];
    int orow[4];
#pragma unroll
    for (int i = 0; i < 4; i++) {
        orow[i] = browA + kgrp * 4 + i;
        dv[i] = rsqrtf((float)(deg[min(orow[i], N_NODES - 1)] + 1));
    }

#pragma unroll
    for (int nt = 0; nt < 4; nt++) {
        const int n = nt * 16 + row16;
        bf16x8 bh[4], bl[4];
#pragma unroll
        for (int ks = 0; ks < 4; ks++) {
            bh[ks] = *(const bf16x8*)&WtH[n][ks * 32 + kgrp * 8];
            bl[ks] = *(const bf16x8*)&WtL[n][ks * 32 + kgrp * 8];
        }
        f32x4 acc = {0.f, 0.f, 0.f, 0.f};
#pragma unroll
        for (int ks = 0; ks < 4; ks++)
            acc = __builtin_amdgcn_mfma_f32_16x16x32_bf16(ah[ks], bh[ks], acc, 0, 0, 0);
#pragma unroll
        for (int ks = 0; ks < 4; ks++)
            acc = __builtin_amdgcn_mfma_f32_16x16x32_bf16(al[ks], bh[ks], acc, 0, 0, 0);
#pragma unroll
        for (int ks = 0; ks < 4; ks++)
            acc = __builtin_amdgcn_mfma_f32_16x16x32_bf16(ah[ks], bl[ks], acc, 0, 0, 0);
#pragma unroll
        for (int i = 0; i < 4; i++) {
            if (orow[i] < N_NODES) {
                float g = acc[i] * dv[i];
                gm[(size_t)orow[i] * HID + nt * 16 + row16] =
                    __bfloat16_as_ushort(__float2bfloat16(g));
            }
        }
    }
}

// ------- k_aggcsr: LOCAL sort (2 coalesced record passes -> LDS srcs) + -------
// r5-proven register-accumulating gather + epilogue. One block per bucket.
// No fp32 atomics anywhere; no global srcs/row_se traffic; 35 KB LDS -> 4 blk/CU.
__global__ __launch_bounds__(512) void k_aggcsr(const unsigned short* __restrict__ gm,
                                                const unsigned* __restrict__ gbuf,
                                                const int* __restrict__ bucketcnt,
                                                const float* __restrict__ bconv,
                                                const float* __restrict__ Wlin,
                                                const float* __restrict__ blin,
                                                float* __restrict__ out) {
    __shared__ unsigned srcs_l[MAXPB];   // 32 KB: src ids grouped by dst
    __shared__ int lcnt[256];
    __shared__ int pre[256];
    __shared__ int cur[256];
    const int b = blockIdx.x, t = threadIdx.x;
    const int n = bucketcnt[b];
    const unsigned* reg = gbuf + (size_t)b * MAXPB;

    // ---- pass 1: count per-dst (coalesced global read) ----
    if (t < 256) lcnt[t] = 0;
    __syncthreads();
    for (int j = t; j < n; j += 512) atomicAdd(&lcnt[reg[j] >> 17], 1);
    __syncthreads();
    int my = 0;
    if (t < 256) { my = lcnt[t]; pre[t] = my; }
    __syncthreads();
    for (int o = 1; o < 256; o <<= 1) {
        int v = 0;
        if (t < 256 && t >= o) v = pre[t - o];
        __syncthreads();
        if (t < 256) pre[t] += v;
        __syncthreads();
    }
    if (t < 256) cur[t] = pre[t] - my;   // exclusive prefix within bucket
    __syncthreads();
    // ---- pass 2: place src ids grouped by dst (re-read records, 16 KB) ----
    for (int j = t; j < n; j += 512) {
        const unsigned rec = reg[j];
        const int pos = atomicAdd(&cur[rec >> 17], 1);
        srcs_l[pos] = rec & 0x1FFFFu;
    }
    __syncthreads();

    // ---- gather + epilogue: 32 groups x 16 lanes; 8 dsts per group ----
    const int g = t >> 4, d4 = t & 15;
    for (int p = 0; p < 8; p++) {
        const int cl = p * 32 + g;
        const int c = b * 256 + cl;
        if (c >= N_NODES) continue;      // whole 16-lane group agrees
        const int myc = lcnt[cl];
        const int end = pre[cl];
        const int beg = end - myc;

        // self-loop term g[c]
        const uint2 s0 = loadg(gm, c, d4);
        float a0 = bf2f_lo(s0.x), a1 = bf2f_hi(s0.x);
        float a2 = bf2f_lo(s0.y), a3 = bf2f_hi(s0.y);

        if (beg < end) {
            const int last = end - 1;
            int r[8];
            uint2 wa[8], wb[8];
#pragma unroll
            for (int u = 0; u < 8; u++) r[u] = (int)srcs_l[min(beg + u, last)];
#pragma unroll
            for (int u = 0; u < 8; u++) wa[u] = loadg(gm, r[u], d4);
            bool haveB = (beg + 8 < end);
            if (haveB) {
#pragma unroll
                for (int u = 0; u < 8; u++) r[u] = (int)srcs_l[min(beg + 8 + u, last)];
#pragma unroll
                for (int u = 0; u < 8; u++) wb[u] = loadg(gm, r[u], d4);
            }
            int j = beg;
            while (true) {
#pragma unroll
                for (int u = 0; u < 8; u++) {
                    const unsigned m = (j + u < end) ? 0xffffffffu : 0u;
                    a0 += bf2f_lo(wa[u].x & m); a1 += bf2f_hi(wa[u].x & m);
                    a2 += bf2f_lo(wa[u].y & m); a3 += bf2f_hi(wa[u].y & m);
                }
                j += 8;
                if (!haveB) break;
                const bool haveN = (j + 8 < end);
                if (haveN) {
#pragma unroll
                    for (int u = 0; u < 8; u++) r[u] = (int)srcs_l[min(j + 8 + u, last)];
#pragma unroll
                    for (int u = 0; u < 8; u++) wa[u] = loadg(gm, r[u], d4);
                }
#pragma unroll
                for (int u = 0; u < 8; u++) {
                    const unsigned m = (j + u < end) ? 0xffffffffu : 0u;
                    a0 += bf2f_lo(wb[u].x & m); a1 += bf2f_hi(wb[u].x & m);
                    a2 += bf2f_lo(wb[u].y & m); a3 += bf2f_hi(wb[u].y & m);
                }
                j += 8;
                if (!haveN) break;
                haveB = (j + 8 < end);
                if (haveB) {
#pragma unroll
                    for (int u = 0; u < 8; u++) r[u] = (int)srcs_l[min(j + 8 + u, last)];
#pragma unroll
                    for (int u = 0; u < 8; u++) wb[u] = loadg(gm, r[u], d4);
                }
            }
        }

        const float dv = rsqrtf((float)(myc + 1));
        const float4 bc4 = *(const float4*)(bconv + (d4 << 2));
        float v0 = fmaxf(a0 * dv + bc4.x, 0.f);
        float v1 = fmaxf(a1 * dv + bc4.y, 0.f);
        float v2 = fmaxf(a2 * dv + bc4.z, 0.f);
        float v3 = fmaxf(a3 * dv + bc4.w, 0.f);

        // dropout: per-element threefry mapping i = c*64 + d
        const unsigned ib = (unsigned)(c * HID + (d4 << 2));
        unsigned o0, o1;
        threefry2x32_k42(0u, ib + 0u, o0, o1);
        v0 = ((o0 ^ o1) & 0x80000000u) ? 0.f : v0 * 2.f;
        threefry2x32_k42(0u, ib + 1u, o0, o1);
        v1 = ((o0 ^ o1) & 0x80000000u) ? 0.f : v1 * 2.f;
        threefry2x32_k42(0u, ib + 2u, o0, o1);
        v2 = ((o0 ^ o1) & 0x80000000u) ? 0.f : v2 * 2.f;
        threefry2x32_k42(0u, ib + 3u, o0, o1);
        v3 = ((o0 ^ o1) & 0x80000000u) ? 0.f : v3 * 2.f;

        // [64 -> 2] matvec partials: Wlin row-major [64][2]
        const float4 wl0 = *(const float4*)(Wlin + (d4 << 3));
        const float4 wl1 = *(const float4*)(Wlin + (d4 << 3) + 4);
        float p0 = v0 * wl0.x + v1 * wl0.z + v2 * wl1.x + v3 * wl1.z;
        float p1 = v0 * wl0.y + v1 * wl0.w + v2 * wl1.y + v3 * wl1.w;

        // reduce across the 16 lanes of this group (xor masks stay in-group)
#pragma unroll
        for (int off = 8; off; off >>= 1) {
            p0 += __shfl_xor(p0, off);
            p1 += __shfl_xor(p1, off);
        }
        if (d4 == 0) {
            *(float2*)(out + (size_t)c * 2) = make_float2(p0 + blin[0], p1 + blin[1]);
        }
    }
}

extern "C" void kernel_launch(void* const* d_in, const int* in_sizes, int n_in,
                              void* d_out, int out_size, void* d_ws, size_t ws_size,
                              hipStream_t stream) {
    // Map inputs BY ELEMENT COUNT (all unique) — robust to positional order.
    const float* x  = (const float*)d_in[0];
    const void*  ei = d_in[1];
    const float* Wc = (const float*)d_in[2];
    const float* bc = (const float*)d_in[3];
    const float* Wl = (const float*)d_in[4];
    const float* bl = (const float*)d_in[5];
    for (int i = 0; i < n_in; i++) {
        switch (in_sizes[i]) {
            case N_NODES * IN_DIM:   x  = (const float*)d_in[i]; break;
            case 2 * N_EDGES:
            case 4 * N_EDGES:        ei = d_in[i]; break;
            case IN_DIM * HID:       Wc = (const float*)d_in[i]; break;
            case HID:                bc = (const float*)d_in[i]; break;
            case HID * 2:            Wl = (const float*)d_in[i]; break;
            case 2:                  bl = (const float*)d_in[i]; break;
            default: break;
        }
    }
    float* out = (float*)d_out;

    const int* src = (const int*)ei;            // edge_index[0] (int32, proven r2≡r3)
    const int* dst = (const int*)ei + N_EDGES;  // edge_index[1]

    char* ws = (char*)d_ws;
    size_t off = 0;
    unsigned short* gm = (unsigned short*)(ws + off); off += (size_t)N_NODES * HID * 2;  // 12.8 MB
    int* deg           = (int*)(ws + off);     off += (size_t)N_NODES * 4;               // 400 KB
    int* bucketcnt     = (int*)(ws + off);     off += (size_t)(NB + 64) * 4;             // adjacent to deg
    off = (off + 255) & ~(size_t)255;
    unsigned* gbuf     = (unsigned*)(ws + off); off += (size_t)NB * MAXPB * 4;           // 12.8 MB
    // gbuf holds raw records; k_aggcsr sorts them LOCALLY (LDS) — no CSR pass

    // zero deg + bucketcnt in one memset (contiguous)
    hipMemsetAsync(deg, 0, ((size_t)N_NODES + NB) * 4, stream);
    k_bucket<<<BUCKET_BLOCKS, 512, 0, stream>>>(src, dst, bucketcnt, deg, gbuf);
    k_gemm<<<(N_NODES + 63) / 64, 256, 0, stream>>>(x, Wc, deg, gm);
    k_aggcsr<<<NB, 512, 0, stream>>>(gm, gbuf, bucketcnt, bc, Wl, bl, out);
}

// Round 9
// 179.754 us; speedup vs baseline: 4.8534x; 1.3068x over previous
//
#include <hip/hip_runtime.h>
#include <hip/hip_bf16.h>

#define N_NODES 100000
#define N_EDGES 1600000
#define IN_DIM 128
#define HID 64
#define NB 391                 // buckets of 256 dst nodes
#define EPB 4096               // edges per k_bucket block
#define BUCKET_BLOCKS ((N_EDGES + EPB - 1) / EPB)  // 391
#define MAXPB 8192             // fixed gbuf region per bucket (mean 4092)
#define HALFCAP (MAXPB / 2)    // srcs region per half-bucket (max fill ~2350)

typedef __attribute__((ext_vector_type(8))) short bf16x8;
typedef __attribute__((ext_vector_type(4))) float f32x4;

// ---------------- threefry2x32, key = (0, 42) ----------------
__device__ __forceinline__ unsigned rotl32(unsigned x, unsigned r) {
    return (x << r) | (x >> (32u - r));
}

__device__ __forceinline__ void threefry2x32_k42(unsigned x0, unsigned x1,
                                                 unsigned& o0, unsigned& o1) {
    const unsigned ks0 = 0u;
    const unsigned ks1 = 42u;
    const unsigned ks2 = 0u ^ 42u ^ 0x1BD11BDAu;
    x0 += ks0; x1 += ks1;
    x0 += x1; x1 = rotl32(x1, 13); x1 ^= x0;
    x0 += x1; x1 = rotl32(x1, 15); x1 ^= x0;
    x0 += x1; x1 = rotl32(x1, 26); x1 ^= x0;
    x0 += x1; x1 = rotl32(x1, 6);  x1 ^= x0;
    x0 += ks1; x1 += ks2 + 1u;
    x0 += x1; x1 = rotl32(x1, 17); x1 ^= x0;
    x0 += x1; x1 = rotl32(x1, 29); x1 ^= x0;
    x0 += x1; x1 = rotl32(x1, 16); x1 ^= x0;
    x0 += x1; x1 = rotl32(x1, 24); x1 ^= x0;
    x0 += ks2; x1 += ks0 + 2u;
    x0 += x1; x1 = rotl32(x1, 13); x1 ^= x0;
    x0 += x1; x1 = rotl32(x1, 15); x1 ^= x0;
    x0 += x1; x1 = rotl32(x1, 26); x1 ^= x0;
    x0 += x1; x1 = rotl32(x1, 6);  x1 ^= x0;
    x0 += ks0; x1 += ks1 + 3u;
    x0 += x1; x1 = rotl32(x1, 17); x1 ^= x0;
    x0 += x1; x1 = rotl32(x1, 29); x1 ^= x0;
    x0 += x1; x1 = rotl32(x1, 16); x1 ^= x0;
    x0 += x1; x1 = rotl32(x1, 24); x1 ^= x0;
    x0 += ks1; x1 += ks2 + 4u;
    x0 += x1; x1 = rotl32(x1, 13); x1 ^= x0;
    x0 += x1; x1 = rotl32(x1, 15); x1 ^= x0;
    x0 += x1; x1 = rotl32(x1, 26); x1 ^= x0;
    x0 += x1; x1 = rotl32(x1, 6);  x1 ^= x0;
    x0 += ks2; x1 += ks0 + 5u;
    o0 = x0; o1 = x1;
}

__device__ __forceinline__ float bf2f(unsigned short u) {
    return __uint_as_float((unsigned)u << 16);
}
// low/high bf16 of a packed uint
__device__ __forceinline__ float bf2f_lo(unsigned u) {
    return __uint_as_float(u << 16);
}
__device__ __forceinline__ float bf2f_hi(unsigned u) {
    return __uint_as_float(u & 0xffff0000u);
}
__device__ __forceinline__ uint2 loadg(const unsigned short* __restrict__ gm, int ri, int d4) {
    return *(const uint2*)(gm + ((size_t)ri << 6) + (d4 << 2));
}

// ---- phase 1: bucketed scatter into FIXED regions (r5 pristine — NO deg) ----
// record = (c & 255) << 17 | r   (r < 2^17). LDS count+scan+permute makes the
// global write segmented-contiguous per bucket (~1.3x line amplification).
__global__ __launch_bounds__(512) void k_bucket(const int* __restrict__ src,
                                                const int* __restrict__ dst,
                                                int* __restrict__ bucketcnt,
                                                unsigned* __restrict__ gbuf) {
    __shared__ int cnt[512];
    __shared__ int off[512];
    __shared__ int cur[NB];
    __shared__ int gbase[NB];
    __shared__ unsigned buf[EPB];
    __shared__ unsigned short bkt[EPB];
    const int t = threadIdx.x;
    const int e0 = blockIdx.x * EPB;
    const int n = min(EPB, N_EDGES - e0);
    cnt[t] = 0;
    __syncthreads();
    unsigned myrec[EPB / 512];
    int myb[EPB / 512];
#pragma unroll
    for (int k = 0; k < EPB / 512; k++) {
        int e = e0 + k * 512 + t;
        if (e < N_EDGES) {
            int r = src[e];
            int c = dst[e];
            int b = c >> 8;
            myrec[k] = ((unsigned)(c & 255) << 17) | (unsigned)r;
            myb[k] = b;
            atomicAdd(&cnt[b], 1);
        } else {
            myb[k] = -1;
        }
    }
    __syncthreads();
    int own = cnt[t];
    for (int o = 1; o < 512; o <<= 1) {
        int v = (t >= o) ? cnt[t - o] : 0;
        __syncthreads();
        cnt[t] += v;
        __syncthreads();
    }
    off[t] = cnt[t] - own;  // exclusive prefix (records sorted by bucket in buf)
    if (t < NB) {
        cur[t] = off[t];
        gbase[t] = t * MAXPB + (own ? atomicAdd(&bucketcnt[t], own) : 0);
    }
    __syncthreads();
#pragma unroll
    for (int k = 0; k < EPB / 512; k++) {
        if (myb[k] >= 0) {
            int p = atomicAdd(&cur[myb[k]], 1);
            buf[p] = myrec[k];
            bkt[p] = (unsigned short)myb[k];
        }
    }
    __syncthreads();
    for (int j = t; j < n; j += 512) {
        int b = bkt[j];
        gbuf[gbase[b] + (j - off[b])] = buf[j];
    }
}

// ---- phase 2: HALF-bucket CSR build (2 blocks per bucket -> 2x occupancy) ----
// Block hb = b*2+h handles the 128 dsts with (dst_local>>7)==h. Stages the
// bucket's records once (coalesced), counts/scans 128 counters (7 rounds),
// places src ids into its own fixed HALFCAP region of the srcs array.
// No in-place overwrite (sibling block reads the same records) -> no race.
__global__ __launch_bounds__(256) void k_csrh(const unsigned* __restrict__ gbuf,
                                              const int* __restrict__ bucketcnt,
                                              int* __restrict__ srcs,
                                              int2* __restrict__ row_se,
                                              float* __restrict__ dinv) {
    __shared__ unsigned lbuf[MAXPB];  // 32 KB
    __shared__ int lcnt[128];
    __shared__ int pre[128];
    __shared__ int cur[128];
    const int hb = blockIdx.x, t = threadIdx.x;
    const int b = hb >> 1, h = hb & 1;
    const int n = bucketcnt[b];
    const unsigned* reg = gbuf + (size_t)b * MAXPB;
    if (t < 128) lcnt[t] = 0;
    for (int j = t; j < n; j += 256) lbuf[j] = reg[j];
    __syncthreads();
    for (int j = t; j < n; j += 256) {
        const int cl = (int)(lbuf[j] >> 17);
        if ((cl >> 7) == h) atomicAdd(&lcnt[cl & 127], 1);
    }
    __syncthreads();
    int my = 0;
    if (t < 128) { my = lcnt[t]; pre[t] = my; }
    __syncthreads();
    for (int o = 1; o < 128; o <<= 1) {
        int v = 0;
        if (t < 128 && t >= o) v = pre[t - o];
        __syncthreads();
        if (t < 128) pre[t] += v;
        __syncthreads();
    }
    if (t < 128) {
        const int base = hb * HALFCAP + pre[t] - my;  // absolute pos in srcs
        cur[t] = base;
        const int c = b * 256 + h * 128 + t;
        if (c < N_NODES) {
            row_se[c] = make_int2(base, base + my);
            dinv[c] = rsqrtf((float)(my + 1));  // in-degree + self-loop
        }
    }
    __syncthreads();
    for (int j = t; j < n; j += 256) {
        const unsigned rec = lbuf[j];
        const int cl = (int)(rec >> 17);
        if ((cl >> 7) == h) {
            const int pos = atomicAdd(&cur[cl & 127], 1);
            srcs[pos] = (int)(rec & 0x1FFFFu);
        }
    }
}

// ------ g = (x @ W_conv) * dinv[row], bf16 out — MFMA split-bf16 (r5 pristine) ------
// 3-pass split: x=xh+xl, W=Wh+Wl (bf16 each); h = xh@Wh + xl@Wh + xh@Wl.
__global__ __launch_bounds__(256) void k_gemm(const float* __restrict__ x,
                                              const float* __restrict__ W,
                                              const float* __restrict__ dinv,
                                              unsigned short* __restrict__ gm) {
    __shared__ unsigned short WtH[HID][136];
    __shared__ unsigned short WtL[HID][136];
    const int t = threadIdx.x;
    {
        const int n = t & 63;
        const int k0 = (t >> 6) * 32;
        for (int k = k0; k < k0 + 32; k += 2) {
            float w0 = W[(size_t)k * HID + n];
            float w1 = W[(size_t)(k + 1) * HID + n];
            unsigned short h0 = __bfloat16_as_ushort(__float2bfloat16(w0));
            unsigned short h1 = __bfloat16_as_ushort(__float2bfloat16(w1));
            unsigned short l0 = __bfloat16_as_ushort(__float2bfloat16(w0 - bf2f(h0)));
            unsigned short l1 = __bfloat16_as_ushort(__float2bfloat16(w1 - bf2f(h1)));
            *(unsigned*)&WtH[n][k] = (unsigned)h0 | ((unsigned)h1 << 16);
            *(unsigned*)&WtL[n][k] = (unsigned)l0 | ((unsigned)l1 << 16);
        }
    }
    __syncthreads();

    const int wave = t >> 6, lane = t & 63;
    const int row16 = lane & 15;   // A-frag row within tile / B-frag col
    const int kgrp = lane >> 4;    // k-subgroup
    const int browA = blockIdx.x * 64 + wave * 16;

    const int rA = min(browA + row16, N_NODES - 1);  // clamp tail reads
    const float* xr = x + (size_t)rA * IN_DIM + kgrp * 8;
    float xv[32];
#pragma unroll
    for (int ks = 0; ks < 4; ks++) {
        *(f32x4*)&xv[ks * 8]     = *(const f32x4*)(xr + ks * 32);
        *(f32x4*)&xv[ks * 8 + 4] = *(const f32x4*)(xr + ks * 32 + 4);
    }
    bf16x8 ah[4], al[4];
#pragma unroll
    for (int ks = 0; ks < 4; ks++) {
#pragma unroll
        for (int j = 0; j < 8; j++) {
            float v = xv[ks * 8 + j];
            unsigned short h = __bfloat16_as_ushort(__float2bfloat16(v));
            unsigned short l = __bfloat16_as_ushort(__float2bfloat16(v - bf2f(h)));
            ah[ks][j] = (short)h;
            al[ks][j] = (short)l;
        }
    }

    float dv[4];
    int orow[4];
#pragma unroll
    for (int i = 0; i < 4; i++) {
        orow[i] = browA + kgrp * 4 + i;
        dv[i] = dinv[min(orow[i], N_NODES - 1)];
    }

#pragma unroll
    for (int nt = 0; nt < 4; nt++) {
        const int n = nt * 16 + row16;
        bf16x8 bh[4], bl[4];
#pragma unroll
        for (int ks = 0; ks < 4; ks++) {
            bh[ks] = *(const bf16x8*)&WtH[n][ks * 32 + kgrp * 8];
            bl[ks] = *(const bf16x8*)&WtL[n][ks * 32 + kgrp * 8];
        }
        f32x4 acc = {0.f, 0.f, 0.f, 0.f};
#pragma unroll
        for (int ks = 0; ks < 4; ks++)
            acc = __builtin_amdgcn_mfma_f32_16x16x32_bf16(ah[ks], bh[ks], acc, 0, 0, 0);
#pragma unroll
        for (int ks = 0; ks < 4; ks++)
            acc = __builtin_amdgcn_mfma_f32_16x16x32_bf16(al[ks], bh[ks], acc, 0, 0, 0);
#pragma unroll
        for (int ks = 0; ks < 4; ks++)
            acc = __builtin_amdgcn_mfma_f32_16x16x32_bf16(ah[ks], bl[ks], acc, 0, 0, 0);
#pragma unroll
        for (int i = 0; i < 4; i++) {
            if (orow[i] < N_NODES) {
                float g = acc[i] * dv[i];
                gm[(size_t)orow[i] * HID + nt * 16 + row16] =
                    __bfloat16_as_ushort(__float2bfloat16(g));
            }
        }
    }
}

// ------- fused gather + self + bias/relu/dropout + [64->2] matvec (r5 pristine) -------
// 16 lanes per dst (4 dims/lane, dwordx2), 4 dsts/wave. ALL edges processed in
// masked 8-batches, two buffers ping-pong. Extent from row_se[c] (int2).
__global__ __launch_bounds__(256, 4) void k_aggr(const unsigned short* __restrict__ gm,
                                                 const int2* __restrict__ row_se,
                                                 const int* __restrict__ srcs,
                                                 const float* __restrict__ dinv,
                                                 const float* __restrict__ bconv,
                                                 const float* __restrict__ Wlin,
                                                 const float* __restrict__ blin,
                                                 float* __restrict__ out) {
    const int c  = blockIdx.x * 16 + (threadIdx.x >> 4);  // dst node, group of 16 lanes
    const int d4 = threadIdx.x & 15;                      // dim quad: dims [4*d4, 4*d4+4)
    const int2 se = row_se[c];
    const int beg = se.x;
    const int end = se.y;

    // self-loop term g[c] (accumulation order: self first, then j asc)
    const uint2 s0 = loadg(gm, c, d4);
    float a0 = bf2f_lo(s0.x), a1 = bf2f_hi(s0.x);
    float a2 = bf2f_lo(s0.y), a3 = bf2f_hi(s0.y);

    if (beg < end) {
        const int last = end - 1;
        int r[8];
        uint2 wa[8], wb[8];
        // batch 0 -> wa
#pragma unroll
        for (int u = 0; u < 8; u++) r[u] = srcs[min(beg + u, last)];
#pragma unroll
        for (int u = 0; u < 8; u++) wa[u] = loadg(gm, r[u], d4);
        bool haveB = (beg + 8 < end);
        if (haveB) {
#pragma unroll
            for (int u = 0; u < 8; u++) r[u] = srcs[min(beg + 8 + u, last)];
#pragma unroll
            for (int u = 0; u < 8; u++) wb[u] = loadg(gm, r[u], d4);
        }
        int j = beg;
        while (true) {
            // accumulate wa for [j, j+8), masked (masked adds contribute exact 0.0f)
#pragma unroll
            for (int u = 0; u < 8; u++) {
                const unsigned m = (j + u < end) ? 0xffffffffu : 0u;
                a0 += bf2f_lo(wa[u].x & m); a1 += bf2f_hi(wa[u].x & m);
                a2 += bf2f_lo(wa[u].y & m); a3 += bf2f_hi(wa[u].y & m);
            }
            j += 8;
            if (!haveB) break;
            // prefetch batch after wb into wa (issues before wb's accumulate)
            const bool haveN = (j + 8 < end);
            if (haveN) {
#pragma unroll
                for (int u = 0; u < 8; u++) r[u] = srcs[min(j + 8 + u, last)];
#pragma unroll
                for (int u = 0; u < 8; u++) wa[u] = loadg(gm, r[u], d4);
            }
            // accumulate wb for [j, j+8)
#pragma unroll
            for (int u = 0; u < 8; u++) {
                const unsigned m = (j + u < end) ? 0xffffffffu : 0u;
                a0 += bf2f_lo(wb[u].x & m); a1 += bf2f_hi(wb[u].x & m);
                a2 += bf2f_lo(wb[u].y & m); a3 += bf2f_hi(wb[u].y & m);
            }
            j += 8;
            if (!haveN) break;
            haveB = (j + 8 < end);
            if (haveB) {
#pragma unroll
                for (int u = 0; u < 8; u++) r[u] = srcs[min(j + 8 + u, last)];
#pragma unroll
                for (int u = 0; u < 8; u++) wb[u] = loadg(gm, r[u], d4);
            }
        }
    }

    const float dv = dinv[c];
    const float4 bc4 = *(const float4*)(bconv + (d4 << 2));
    float v0 = fmaxf(a0 * dv + bc4.x, 0.f);
    float v1 = fmaxf(a1 * dv + bc4.y, 0.f);
    float v2 = fmaxf(a2 * dv + bc4.z, 0.f);
    float v3 = fmaxf(a3 * dv + bc4.w, 0.f);

    // dropout: per-element threefry mapping i = c*64 + d
    const unsigned ib = (unsigned)(c * HID + (d4 << 2));
    unsigned o0, o1;
    threefry2x32_k42(0u, ib + 0u, o0, o1);
    v0 = ((o0 ^ o1) & 0x80000000u) ? 0.f : v0 * 2.f;
    threefry2x32_k42(0u, ib + 1u, o0, o1);
    v1 = ((o0 ^ o1) & 0x80000000u) ? 0.f : v1 * 2.f;
    threefry2x32_k42(0u, ib + 2u, o0, o1);
    v2 = ((o0 ^ o1) & 0x80000000u) ? 0.f : v2 * 2.f;
    threefry2x32_k42(0u, ib + 3u, o0, o1);
    v3 = ((o0 ^ o1) & 0x80000000u) ? 0.f : v3 * 2.f;

    // [64 -> 2] matvec partials: Wlin row-major [64][2]; lane covers rows 4*d4..4*d4+3
    const float4 wl0 = *(const float4*)(Wlin + (d4 << 3));      // rows 4d4, 4d4+1
    const float4 wl1 = *(const float4*)(Wlin + (d4 << 3) + 4);  // rows 4d4+2, 4d4+3
    float p0 = v0 * wl0.x + v1 * wl0.z + v2 * wl1.x + v3 * wl1.z;
    float p1 = v0 * wl0.y + v1 * wl0.w + v2 * wl1.y + v3 * wl1.w;

    // reduce across the 16 lanes of this dst group (aligned, so xor stays in-group)
#pragma unroll
    for (int off = 8; off; off >>= 1) {
        p0 += __shfl_xor(p0, off);
        p1 += __shfl_xor(p1, off);
    }
    if (d4 == 0) {
        *(float2*)(out + (size_t)c * 2) = make_float2(p0 + blin[0], p1 + blin[1]);
    }
}

extern "C" void kernel_launch(void* const* d_in, const int* in_sizes, int n_in,
                              void* d_out, int out_size, void* d_ws, size_t ws_size,
                              hipStream_t stream) {
    // Map inputs BY ELEMENT COUNT (all unique) — robust to positional order.
    const float* x  = (const float*)d_in[0];
    const void*  ei = d_in[1];
    const float* Wc = (const float*)d_in[2];
    const float* bc = (const float*)d_in[3];
    const float* Wl = (const float*)d_in[4];
    const float* bl = (const float*)d_in[5];
    for (int i = 0; i < n_in; i++) {
        switch (in_sizes[i]) {
            case N_NODES * IN_DIM:   x  = (const float*)d_in[i]; break;
            case 2 * N_EDGES:
            case 4 * N_EDGES:        ei = d_in[i]; break;
            case IN_DIM * HID:       Wc = (const float*)d_in[i]; break;
            case HID:                bc = (const float*)d_in[i]; break;
            case HID * 2:            Wl = (const float*)d_in[i]; break;
            case 2:                  bl = (const float*)d_in[i]; break;
            default: break;
        }
    }
    float* out = (float*)d_out;

    const int* src = (const int*)ei;            // edge_index[0] (int32, proven r2≡r3)
    const int* dst = (const int*)ei + N_EDGES;  // edge_index[1]

    char* ws = (char*)d_ws;
    size_t off = 0;
    unsigned short* gm = (unsigned short*)(ws + off); off += (size_t)N_NODES * HID * 2;  // 12.8 MB
    float* dinv        = (float*)(ws + off);   off += (size_t)N_NODES * 4;               // 0.4 MB
    int2*  row_se      = (int2*)(ws + off);    off += (size_t)N_NODES * 8;               // 0.8 MB
    int*   bucketcnt   = (int*)(ws + off);     off += (size_t)(NB + 64) * 4;
    off = (off + 255) & ~(size_t)255;
    unsigned* gbuf     = (unsigned*)(ws + off); off += (size_t)NB * MAXPB * 4;           // 12.8 MB
    int*   srcs        = (int*)(ws + off);     off += (size_t)NB * MAXPB * 4;            // 12.8 MB

    hipMemsetAsync(bucketcnt, 0, (size_t)NB * 4, stream);
    k_bucket<<<BUCKET_BLOCKS, 512, 0, stream>>>(src, dst, bucketcnt, gbuf);
    k_csrh<<<NB * 2, 256, 0, stream>>>(gbuf, bucketcnt, srcs, row_se, dinv);
    k_gemm<<<(N_NODES + 63) / 64, 256, 0, stream>>>(x, Wc, dinv, gm);
    k_aggr<<<(N_NODES + 15) / 16, 256, 0, stream>>>(gm, row_se, srcs,
                                                    dinv, bc, Wl, bl, out);
}